// Round 7
// baseline (2369.813 us; speedup 1.0000x reference)
//
#include <hip/hip_runtime.h>
#include <math.h>

#define NS 512      // N_way*K_shot support samples
#define NQ 65536    // N_way*Q_query rows
#define DD 1024     // feature dim
#define NW 16       // N_way
#define NWG 36      // setup kernel workgroups (<< 256 CUs -> co-resident)

typedef __attribute__((ext_vector_type(8))) short short8x;
typedef __attribute__((ext_vector_type(4))) float floatx4;

static __device__ __forceinline__ unsigned short bf_trunc(float x) {
  return (unsigned short)(__float_as_uint(x) >> 16);
}
static __device__ __forceinline__ float bf_tof(unsigned short h) {
  return __uint_as_float(((unsigned)h) << 16);
}
static __device__ __forceinline__ unsigned short bf_rne(float x) {
  unsigned u = __float_as_uint(x);
  return (unsigned short)((u + 0x7FFFu + ((u >> 16) & 1u)) >> 16);
}

// split f32 -> (hi, lo) bf16 pair, swizzled 8B LDS store. k0 multiple of 4.
#define STASH(Hp, Lp, row, k0, v) do {                                      \
    unsigned e_ = (unsigned)((((row) * 32 + (k0)) ^ (((row) & 7) << 3)));   \
    ushort4 h_, l_;                                                         \
    h_.x = bf_trunc((v).x); l_.x = bf_trunc((v).x - bf_tof(h_.x));          \
    h_.y = bf_trunc((v).y); l_.y = bf_trunc((v).y - bf_tof(h_.y));          \
    h_.z = bf_trunc((v).z); l_.z = bf_trunc((v).z - bf_tof(h_.z));          \
    h_.w = bf_trunc((v).w); l_.w = bf_trunc((v).w - bf_tof(h_.w));          \
    *(ushort4*)&Hp[e_] = h_; *(ushort4*)&Lp[e_] = l_;                       \
  } while (0)

// ---------------- device-wide barrier (36 co-resident WGs) ----------------
__device__ __forceinline__ void gbar(int* cnt, int* gen) {
  __syncthreads();
  if (threadIdx.x == 0) {
    int g = __hip_atomic_load(gen, __ATOMIC_RELAXED, __HIP_MEMORY_SCOPE_AGENT);
    __threadfence();  // release: my writes -> device visible
    int p = __hip_atomic_fetch_add(cnt, 1, __ATOMIC_ACQ_REL, __HIP_MEMORY_SCOPE_AGENT);
    if (p == NWG - 1) {
      __hip_atomic_store(cnt, 0, __ATOMIC_RELAXED, __HIP_MEMORY_SCOPE_AGENT);
      __hip_atomic_store(gen, g + 1, __ATOMIC_RELEASE, __HIP_MEMORY_SCOPE_AGENT);
    } else {
      while (__hip_atomic_load(gen, __ATOMIC_ACQUIRE, __HIP_MEMORY_SCOPE_AGENT) == g)
        __builtin_amdgcn_s_sleep(2);
    }
    __threadfence();  // acquire: invalidate L1 before next phase's loads
  }
  __syncthreads();
}

// wave-0 register potrf of a 64x64 tile staged in LDS (stride 68);
// writes L (lower+diag) and its transpose mirror to K at panel offset j.
__device__ __forceinline__ void potrf_tile(const float* T68, float* __restrict__ K, int j) {
  const int tid = threadIdx.x;
  if (tid < 64) {
    const int r = tid;
    float ar[64];
    #pragma unroll
    for (int c4 = 0; c4 < 16; ++c4)
      *(floatx4*)&ar[c4 * 4] = *(const floatx4*)&T68[r * 68 + c4 * 4];
    #pragma unroll
    for (int c = 0; c < 64; ++c) {
      float colv = ar[c];
      float d = __shfl(colv, c);
      float sq = sqrtf(d);
      float inv = 1.f / sq;
      float x = (r > c) ? colv * inv : ((r == c) ? sq : 0.f);
      ar[c] = x;
      #pragma unroll
      for (int k = c + 1; k < 64; ++k) {
        float xk = __shfl(x, k);
        ar[k] = fmaf(-x, xk, ar[k]);   // junk in upper region, never read
      }
    }
    #pragma unroll
    for (int c = 0; c < 64; ++c) {
      if (c <= r) K[(size_t)(j + r) * NS + j + c] = ar[c];
      if (c < r)  K[(size_t)(j + c) * NS + j + r] = ar[c];   // mirror
    }
  }
}

// wave-0 lockstep lower-triangular solve of 64x16 block (validated r4 logic).
// P: LDS diag tile (stride 68, lower=L). Writes WsT (LDS, stride 68) + Wg.
__device__ __forceinline__ void solve_lower(const float* P, const float* invd,
                                            const float* __restrict__ Wsrc16,
                                            float* WsT, float* __restrict__ Wg, int j) {
  const int tid = threadIdx.x;
  if (tid < 64) {
    const int n = tid & 15, rq = tid >> 4;
    float w16[16];
    #pragma unroll
    for (int i = 0; i < 16; ++i) w16[i] = Wsrc16[(size_t)(rq + 4 * i) * 16 + n];
    #pragma unroll
    for (int g = 0; g < 16; ++g) {
      floatx4 p[16];
      #pragma unroll
      for (int i = 0; i < 16; ++i) p[i] = *(const floatx4*)&P[(rq + 4 * i) * 68 + 4 * g];
      #pragma unroll
      for (int cj = 0; cj < 4; ++cj) {
        const int c = 4 * g + cj;
        float xc = __shfl(w16[c >> 2], ((c & 3) << 4) + n) * invd[c];
        if (rq == (c & 3)) w16[c >> 2] = xc;
        #pragma unroll
        for (int i = 0; i < 16; ++i) {
          int r = rq + 4 * i;
          if (r > c) w16[i] -= p[i][cj] * xc;
        }
      }
    }
    #pragma unroll
    for (int i = 0; i < 16; ++i) {
      WsT[n * 68 + rq + 4 * i] = w16[i];
      Wg[(size_t)(j + rq + 4 * i) * 16 + n] = w16[i];
    }
  }
}

// wave-0 lockstep upper-triangular solve (L^T) of 64x16 block (validated r4).
// P upper triangle = L^T mirror. Reads Wsrc16 (global), writes Wg.
__device__ __forceinline__ void solve_upper(const float* P, const float* invd,
                                            const float* __restrict__ Wsrc16,
                                            float* __restrict__ Wg, int j) {
  const int tid = threadIdx.x;
  if (tid < 64) {
    const int n = tid & 15, rq = tid >> 4;
    float w16[16];
    #pragma unroll
    for (int i = 0; i < 16; ++i) w16[i] = Wsrc16[(size_t)(rq + 4 * i) * 16 + n];
    #pragma unroll
    for (int g = 15; g >= 0; --g) {
      floatx4 p[16];
      #pragma unroll
      for (int i = 0; i < 16; ++i) p[i] = *(const floatx4*)&P[(rq + 4 * i) * 68 + 4 * g];
      #pragma unroll
      for (int cj = 3; cj >= 0; --cj) {
        const int c = 4 * g + cj;
        float xc = __shfl(w16[c >> 2], ((c & 3) << 4) + n) * invd[c];
        if (rq == (c & 3)) w16[c >> 2] = xc;
        #pragma unroll
        for (int i = 0; i < 16; ++i) {
          int r = rq + 4 * i;
          if (r < c) w16[i] -= p[i][cj] * xc;
        }
      }
    }
    #pragma unroll
    for (int i = 0; i < 16; ++i)
      Wg[(size_t)(j + rq + 4 * i) * 16 + n] = w16[i];
  }
}

// ==================== one-launch setup: norms + Kss + Cholesky + solve ====================
__global__ __launch_bounds__(256) void setup_all(const float* __restrict__ Zs,
                                                 const int* __restrict__ Ys,
                                                 const float* __restrict__ log_ls,
                                                 const float* __restrict__ log_noise,
                                                 float* __restrict__ K,
                                                 float* __restrict__ sn,
                                                 float* __restrict__ Wg,
                                                 unsigned short* __restrict__ alpha_t,
                                                 int* cnt, int* gen) {
  __shared__ float pf[13184];   // 52.7 KB pool, phase-aliased
  const int wg = blockIdx.x, tid = threadIdx.x;

  // ---- phase 0: Zs row norms + W one-hot init ----
  {
    int wave = tid >> 6, lane = tid & 63;
    for (int r = wg * 4 + wave; r < NS; r += NWG * 4) {
      const float* row = Zs + (size_t)r * DD;
      float s = 0.f;
      #pragma unroll
      for (int i = 0; i < 4; ++i) {
        float4 v = *(const float4*)(row + 4 * lane + 256 * i);
        s += v.x * v.x + v.y * v.y + v.z * v.z + v.w * v.w;
      }
      #pragma unroll
      for (int off = 32; off; off >>= 1) s += __shfl_xor(s, off);
      if (lane == 0) sn[r] = s;
    }
    int flat = wg * 256 + tid;
    if (flat < NS * NW) Wg[flat] = (Ys[flat >> 4] == (flat & 15)) ? 1.f : 0.f;
  }
  gbar(cnt, gen);

  // ---- phase K: Kss lower-tri tiles (1 per WG, 36 tiles) + potrf(0) on WG0 ----
  {
    int by = 0, accv = 0;
    while (accv + by + 1 <= wg) { accv += by + 1; ++by; }
    int bx = wg - accv;
    const int rb = by * 64, cb = bx * 64;
    float* At = pf;             // [16][68]
    float* Bt = pf + 1088;      // [16][68]
    float* Tile = pf + 8832;    // [64][68] (WG0 potrf hand-off)
    const int tx = tid & 15, ty = tid >> 4;
    const int srow = tid & 63, skq = (tid >> 6) << 2;
    float acc[4][4] = {};
    for (int kk = 0; kk < DD; kk += 16) {
      __syncthreads();
      float4 a = *(const float4*)(Zs + (size_t)(rb + srow) * DD + kk + skq);
      float4 b = *(const float4*)(Zs + (size_t)(cb + srow) * DD + kk + skq);
      At[(skq + 0) * 68 + srow] = a.x; At[(skq + 1) * 68 + srow] = a.y;
      At[(skq + 2) * 68 + srow] = a.z; At[(skq + 3) * 68 + srow] = a.w;
      Bt[(skq + 0) * 68 + srow] = b.x; Bt[(skq + 1) * 68 + srow] = b.y;
      Bt[(skq + 2) * 68 + srow] = b.z; Bt[(skq + 3) * 68 + srow] = b.w;
      __syncthreads();
      #pragma unroll
      for (int k = 0; k < 16; ++k) {
        floatx4 av = *(const floatx4*)&At[k * 68 + ty * 4];
        floatx4 bv = *(const floatx4*)&Bt[k * 68 + tx * 4];
        #pragma unroll
        for (int i = 0; i < 4; ++i)
          #pragma unroll
          for (int jj = 0; jj < 4; ++jj)
            acc[i][jj] = fmaf(av[i], bv[jj], acc[i][jj]);
      }
    }
    float inv2 = 0.5f * expf(-2.f * log_ls[0]);
    float noise = expf(2.f * log_noise[0]);
    #pragma unroll
    for (int i = 0; i < 4; ++i)
      #pragma unroll
      for (int jj = 0; jj < 4; ++jj) {
        int r = rb + ty * 4 + i, c = cb + tx * 4 + jj;
        float d2 = fmaxf(sn[r] + sn[c] - 2.f * acc[i][jj], 0.f);
        float v = expf(-d2 * inv2);
        if (r == c) v += noise;
        K[(size_t)r * NS + c] = v;
        if (wg == 0) Tile[(ty * 4 + i) * 68 + tx * 4 + jj] = v;
      }
    if (wg == 0) {
      __syncthreads();
      potrf_tile(Tile, K, 0);
    }
  }
  gbar(cnt, gen);

  // ---- Cholesky panels jb=0..6: trsm phase / [syrk + potrf(jb+1) + fwd-solve(jb)] phase ----
  for (int jb = 0; jb < 7; ++jb) {
    const int j = jb << 6;
    // --- phase T: trsm rows below panel jb (rows interleaved across WGs) ---
    {
      float* Ld = pf;            // [64][68]
      float* invd = pf + 4416;   // [64]
      #pragma unroll
      for (int it = 0; it < 4; ++it) {
        int flat = tid + 256 * it;
        int r = flat >> 4, c4 = (flat & 15) * 4;
        *(floatx4*)&Ld[r * 68 + c4] = *(const floatx4*)&K[(size_t)(j + r) * NS + j + c4];
      }
      __syncthreads();
      if (tid < 64) invd[tid] = 1.f / Ld[tid * 68 + tid];
      __syncthreads();
      const int r0 = j + 64 + wg + NWG * tid;
      if (r0 < NS) {
        float xr[64];
        #pragma unroll
        for (int c4 = 0; c4 < 16; ++c4)
          *(floatx4*)&xr[c4 * 4] = *(const floatx4*)&K[(size_t)r0 * NS + j + c4 * 4];
        #pragma unroll
        for (int g = 0; g < 16; ++g) {
          float v0 = xr[4 * g], v1 = xr[4 * g + 1], v2 = xr[4 * g + 2], v3 = xr[4 * g + 3];
          for (int kb = 0; kb < g; ++kb) {
            floatx4 x4 = *(const floatx4*)&xr[4 * kb];
            floatx4 l0 = *(const floatx4*)&Ld[(4 * g + 0) * 68 + 4 * kb];
            floatx4 l1 = *(const floatx4*)&Ld[(4 * g + 1) * 68 + 4 * kb];
            floatx4 l2 = *(const floatx4*)&Ld[(4 * g + 2) * 68 + 4 * kb];
            floatx4 l3 = *(const floatx4*)&Ld[(4 * g + 3) * 68 + 4 * kb];
            v0 -= x4.x * l0.x + x4.y * l0.y + x4.z * l0.z + x4.w * l0.w;
            v1 -= x4.x * l1.x + x4.y * l1.y + x4.z * l1.z + x4.w * l1.w;
            v2 -= x4.x * l2.x + x4.y * l2.y + x4.z * l2.z + x4.w * l2.w;
            v3 -= x4.x * l3.x + x4.y * l3.y + x4.z * l3.z + x4.w * l3.w;
          }
          const int c0 = 4 * g;
          float x0 = v0 * invd[c0];
          v1 -= x0 * Ld[(c0 + 1) * 68 + c0];
          float x1 = v1 * invd[c0 + 1];
          v2 -= x0 * Ld[(c0 + 2) * 68 + c0] + x1 * Ld[(c0 + 2) * 68 + c0 + 1];
          float x2 = v2 * invd[c0 + 2];
          v3 -= x0 * Ld[(c0 + 3) * 68 + c0] + x1 * Ld[(c0 + 3) * 68 + c0 + 1] + x2 * Ld[(c0 + 3) * 68 + c0 + 2];
          float x3 = v3 * invd[c0 + 3];
          xr[c0] = x0; xr[c0 + 1] = x1; xr[c0 + 2] = x2; xr[c0 + 3] = x3;
        }
        #pragma unroll
        for (int c4 = 0; c4 < 16; ++c4)
          *(floatx4*)(K + (size_t)r0 * NS + j + c4 * 4) = *(const floatx4*)&xr[c4 * 4];
        #pragma unroll
        for (int c = 0; c < 64; ++c)
          K[(size_t)(j + c) * NS + r0] = xr[c];   // mirror (L^T)
      }
    }
    gbar(cnt, gen);

    // --- phase S: syrk trailing tiles (WG<nt); WG0 also potrf(jb+1); WG35 fwd-solve(jb) ---
    {
      const int T = 7 - jb;
      const int nt = T * (T + 1) / 2;
      if (wg < nt) {
        int ti = 0, a2 = 0;
        while (a2 + ti + 1 <= wg) { a2 += ti + 1; ++ti; }
        int tj = wg - a2;
        const int rbt = j + 64 + ti * 64, cbt = j + 64 + tj * 64;
        float* A = pf;            // [64][69]
        float* B = pf + 4416;     // [64][69]
        float* Tile = pf + 8832;  // [64][68] (WG0 only)
        for (int i = tid; i < 4096; i += 256) {
          int r = i >> 6, k = i & 63;
          A[r * 69 + k] = K[(size_t)(rbt + r) * NS + j + k];
          B[r * 69 + k] = K[(size_t)(cbt + r) * NS + j + k];
        }
        __syncthreads();
        const int tx = tid & 15, ty = tid >> 4;
        float acc[4][4] = {};
        for (int k = 0; k < 64; ++k) {
          float aa[4], bb[4];
          #pragma unroll
          for (int i = 0; i < 4; ++i) aa[i] = A[(ty * 4 + i) * 69 + k];
          #pragma unroll
          for (int i = 0; i < 4; ++i) bb[i] = B[(tx * 4 + i) * 69 + k];
          #pragma unroll
          for (int i = 0; i < 4; ++i)
            #pragma unroll
            for (int jj = 0; jj < 4; ++jj)
              acc[i][jj] = fmaf(aa[i], bb[jj], acc[i][jj]);
        }
        #pragma unroll
        for (int i = 0; i < 4; ++i)
          #pragma unroll
          for (int jj = 0; jj < 4; ++jj) {
            float* cp = &K[(size_t)(rbt + ty * 4 + i) * NS + cbt + tx * 4 + jj];
            float nv = *cp - acc[i][jj];
            *cp = nv;
            if (wg == 0) Tile[(ty * 4 + i) * 68 + tx * 4 + jj] = nv;
          }
        if (wg == 0) {
          __syncthreads();
          potrf_tile(Tile, K, j + 64);
        }
      } else if (wg == 35) {
        // forward solve of W block jb + rank-64 update of all rows below
        float* P = pf;            // [64][68]
        float* invd = pf + 4416;  // [64]
        float* WsT = pf + 5504;   // [16][68]
        #pragma unroll
        for (int it = 0; it < 4; ++it) {
          int flat = tid + 256 * it;
          int r = flat >> 4, c4 = (flat & 15) * 4;
          *(floatx4*)&P[r * 68 + c4] = *(const floatx4*)&K[(size_t)(j + r) * NS + j + c4];
        }
        __syncthreads();
        if (tid < 64) invd[tid] = 1.f / P[tid * 68 + tid];
        solve_lower(P, invd, Wg + (size_t)j * 16, WsT, Wg, j);
        __syncthreads();
        const int nrows = NS - j - 64;
        for (int flat = tid; flat < nrows * 16; flat += 256) {
          int row = j + 64 + (flat >> 4), nn = flat & 15;
          float s = Wg[(size_t)row * 16 + nn];
          const float* lrow = &K[(size_t)row * NS + j];
          #pragma unroll
          for (int g = 0; g < 16; ++g) {
            floatx4 lv = *(const floatx4*)&lrow[4 * g];
            floatx4 wv = *(const floatx4*)&WsT[nn * 68 + 4 * g];
            s -= lv.x * wv.x + lv.y * wv.y + lv.z * wv.z + lv.w * wv.w;
          }
          Wg[(size_t)row * 16 + nn] = s;
        }
      }
    }
    gbar(cnt, gen);
  }

  // ---- phase X7: forward+backward solve of block 7 (WG35) ----
  {
    const int j = 448;
    if (wg == 35) {
      float* P = pf;
      float* invd = pf + 4416;
      float* WsT = pf + 5504;
      #pragma unroll
      for (int it = 0; it < 4; ++it) {
        int flat = tid + 256 * it;
        int r = flat >> 4, c4 = (flat & 15) * 4;
        *(floatx4*)&P[r * 68 + c4] = *(const floatx4*)&K[(size_t)(j + r) * NS + j + c4];
      }
      __syncthreads();
      if (tid < 64) invd[tid] = 1.f / P[tid * 68 + tid];
      solve_lower(P, invd, Wg + (size_t)j * 16, WsT, Wg, j);
      // same wave continues: upper solve reads its own Wg writes
      solve_upper(P, invd, Wg + (size_t)j * 16, Wg, j);
    }
  }
  gbar(cnt, gen);

  // ---- backward: BU(jb) update rows above, then BD(jb-1) solve; jb = 7..1 ----
  for (int jb = 7; jb >= 1; --jb) {
    const int j = jb << 6;
    // --- BU(jb): all WGs update rows r < j with solved block jb ---
    {
      float* Wst = pf;   // [16][68] transposed block
      for (int e = tid; e < 1024; e += 256) {
        int c = e >> 4, n = e & 15;
        Wst[n * 68 + c] = Wg[(size_t)(j + c) * 16 + n];
      }
      __syncthreads();
      const int row = wg + NWG * (tid >> 4);
      const int nn = tid & 15;
      if (row < j) {
        float s = Wg[(size_t)row * 16 + nn];
        const float* lrow = &K[(size_t)row * NS + j];   // upper mirror = L^T
        #pragma unroll
        for (int g = 0; g < 16; ++g) {
          floatx4 lv = *(const floatx4*)&lrow[4 * g];
          floatx4 wv = *(const floatx4*)&Wst[nn * 68 + 4 * g];
          s -= lv.x * wv.x + lv.y * wv.y + lv.z * wv.z + lv.w * wv.w;
        }
        Wg[(size_t)row * 16 + nn] = s;
      }
    }
    gbar(cnt, gen);
    // --- BD(jb-1): WG35 upper-solve block jb-1 ---
    {
      const int j2 = (jb - 1) << 6;
      if (wg == 35) {
        float* P = pf;
        float* invd = pf + 4416;
        #pragma unroll
        for (int it = 0; it < 4; ++it) {
          int flat = tid + 256 * it;
          int r = flat >> 4, c4 = (flat & 15) * 4;
          *(floatx4*)&P[r * 68 + c4] = *(const floatx4*)&K[(size_t)(j2 + r) * NS + j2 + c4];
        }
        __syncthreads();
        if (tid < 64) invd[tid] = 1.f / P[tid * 68 + tid];
        solve_upper(P, invd, Wg + (size_t)j2 * 16, Wg, j2);
      }
    }
    gbar(cnt, gen);
  }

  // ---- final: alpha_t = bf16(W)^T ----
  {
    int flat = wg * 256 + tid;
    if (flat < NS * NW) {
      int r = flat >> 4, nn = flat & 15;
      alpha_t[(size_t)nn * NS + r] = bf_rne(Wg[(size_t)r * 16 + nn]);
    }
  }
}

// ---------------- fused: split-bf16 MFMA Gram -> exp -> MFMA PV -> softmax ----------------
__global__ __launch_bounds__(512) void fused_v2(const float* __restrict__ Zq,
                                                const float* __restrict__ Zs,
                                                const float* __restrict__ sn,
                                                const unsigned short* __restrict__ alpha_t,
                                                const float* __restrict__ log_ls,
                                                float* __restrict__ out) {
  __shared__ __align__(16) unsigned short LB[32768];  // 64 KB, unioned
  __shared__ float qnl[128];
  __shared__ float snl[256];
  unsigned short* AhB = LB;            // Zq hi  [128][32]
  unsigned short* AlB = LB + 4096;     // Zq lo
  unsigned short* BhB = LB + 8192;     // Zs hi  [256][32]
  unsigned short* BlB = LB + 16384;    // Zs lo
  unsigned short* KqB = LB;            // Kq bf16 [128][256] (epilogue overlay)

  const int tid = threadIdx.x;
  const int lane = tid & 63;
  const int w = tid >> 6;              // 8 waves: 2(m) x 4(n)
  const int wm = w >> 2, wn = w & 3;
  const int l15 = lane & 15, l4 = lane >> 4;
  const int rb = blockIdx.x * 128;
  const float inv2 = 0.5f * __expf(-2.f * log_ls[0]);
  const unsigned swz = (unsigned)((l15 & 7) << 3);

  if (tid < 128) qnl[tid] = 0.f;
  __syncthreads();

  const int qrow0 = tid >> 3;          // 0..63
  const int qk0 = (tid & 7) * 4;
  const int qrow1 = 64 + qrow0;

  floatx4 facc = {0.f, 0.f, 0.f, 0.f};

  for (int cc = 0; cc < NS; cc += 256) {
    if (tid < 256) snl[tid] = sn[cc + tid];
    floatx4 acc[4][4];
    #pragma unroll
    for (int a = 0; a < 4; ++a)
      #pragma unroll
      for (int b = 0; b < 4; ++b) acc[a][b] = (floatx4){0.f, 0.f, 0.f, 0.f};

    // prefetch kt = 0
    float4 pq0 = *(const float4*)(Zq + (size_t)(rb + qrow0) * DD + qk0);
    float4 pq1 = *(const float4*)(Zq + (size_t)(rb + qrow1) * DD + qk0);
    float4 ps[4];
    #pragma unroll
    for (int u = 0; u < 4; ++u) {
      int idx = tid + (u << 9);
      ps[u] = *(const float4*)(Zs + (size_t)(cc + (idx >> 3)) * DD + ((idx & 7) * 4));
    }

    for (int kt = 0; kt < 32; ++kt) {
      // ---- STORE phase: regs -> swizzled split-bf16 LDS ----
      STASH(AhB, AlB, qrow0, qk0, pq0);
      STASH(AhB, AlB, qrow1, qk0, pq1);
      #pragma unroll
      for (int u = 0; u < 4; ++u) {
        int idx = tid + (u << 9);
        int srow = idx >> 3, sk0 = (idx & 7) * 4;
        STASH(BhB, BlB, srow, sk0, ps[u]);
      }
      if (cc == 0) {  // fold Zq row-norm accumulation into chunk-0 staging
        float s0 = pq0.x * pq0.x + pq0.y * pq0.y + pq0.z * pq0.z + pq0.w * pq0.w;
        float s1 = pq1.x * pq1.x + pq1.y * pq1.y + pq1.z * pq1.z + pq1.w * pq1.w;
        #pragma unroll
        for (int d = 1; d < 8; d <<= 1) { s0 += __shfl_xor(s0, d); s1 += __shfl_xor(s1, d); }
        if ((tid & 7) == 0) { qnl[qrow0] += s0; qnl[qrow1] += s1; }
      }
      __syncthreads();
      // ---- prefetch next iter (hidden under MFMA) ----
      if (kt < 31) {
        int kk2 = (kt + 1) << 5;
        pq0 = *(const float4*)(Zq + (size_t)(rb + qrow0) * DD + kk2 + qk0);
        pq1 = *(const float4*)(Zq + (size_t)(rb + qrow1) * DD + kk2 + qk0);
        #pragma unroll
        for (int u = 0; u < 4; ++u) {
          int idx = tid + (u << 9);
          ps[u] = *(const float4*)(Zs + (size_t)(cc + (idx >> 3)) * DD + kk2 + ((idx & 7) * 4));
        }
      }
      // ---- compute: 16 ds_read_b128 + 48 MFMA ----
      short8x ah[4], al[4], bh[4], bl[4];
      #pragma unroll
      for (int mi = 0; mi < 4; ++mi) {
        unsigned e = (unsigned)((wm * 64 + mi * 16 + l15) * 32 + 8 * l4) ^ swz;
        ah[mi] = *(const short8x*)&AhB[e];
        al[mi] = *(const short8x*)&AlB[e];
      }
      #pragma unroll
      for (int ni = 0; ni < 4; ++ni) {
        unsigned e = (unsigned)((wn * 64 + ni * 16 + l15) * 32 + 8 * l4) ^ swz;
        bh[ni] = *(const short8x*)&BhB[e];
        bl[ni] = *(const short8x*)&BlB[e];
      }
      #pragma unroll
      for (int mi = 0; mi < 4; ++mi)
        #pragma unroll
        for (int ni = 0; ni < 4; ++ni) {
          acc[mi][ni] = __builtin_amdgcn_mfma_f32_16x16x32_bf16(ah[mi], bh[ni], acc[mi][ni], 0, 0, 0);
          acc[mi][ni] = __builtin_amdgcn_mfma_f32_16x16x32_bf16(ah[mi], bl[ni], acc[mi][ni], 0, 0, 0);
          acc[mi][ni] = __builtin_amdgcn_mfma_f32_16x16x32_bf16(al[mi], bh[ni], acc[mi][ni], 0, 0, 0);
        }
      __syncthreads();
    }

    // ---- epilogue: PV B-frags (alpha^T, global/L2), kq -> KqB, PV MFMA ----
    short8x bfr[8];
    #pragma unroll
    for (int s = 0; s < 8; ++s)
      bfr[s] = *(const short8x*)(alpha_t + ((size_t)l15 * NS + cc + 32 * s + 8 * l4));

    #pragma unroll
    for (int mi = 0; mi < 4; ++mi)
      #pragma unroll
      for (int rr = 0; rr < 4; ++rr) {
        int row_l = wm * 64 + mi * 16 + l4 * 4 + rr;
        float qv = qnl[row_l];
        unsigned sw = (unsigned)((row_l & 7) << 3);
        #pragma unroll
        for (int ni = 0; ni < 4; ++ni) {
          int col = wn * 64 + ni * 16 + l15;
          float d2 = fmaxf(qv + snl[col] - 2.f * acc[mi][ni][rr], 0.f);
          float kq = __expf(-d2 * inv2);
          KqB[(unsigned)(row_l * 256 + col) ^ sw] = bf_rne(kq);
        }
      }
    __syncthreads();
    #pragma unroll
    for (int s = 0; s < 8; ++s) {
      unsigned e = (unsigned)((w * 16 + l15) * 256 + 32 * s + 8 * l4) ^ swz;
      short8x ak = *(const short8x*)&KqB[e];
      facc = __builtin_amdgcn_mfma_f32_16x16x32_bf16(ak, bfr[s], facc, 0, 0, 0);
    }
    __syncthreads();
  }

  // ---- softmax over 16 classes (spread across 16-lane groups) ----
  #pragma unroll
  for (int r = 0; r < 4; ++r) {
    float v = facc[r];
    float m = v;
    #pragma unroll
    for (int d = 1; d < 16; d <<= 1) m = fmaxf(m, __shfl_xor(m, d));
    float e = __expf(v - m);
    float s = e;
    #pragma unroll
    for (int d = 1; d < 16; d <<= 1) s += __shfl_xor(s, d);
    out[(size_t)(rb + w * 16 + l4 * 4 + r) * NW + l15] = e / s;
  }
}

extern "C" void kernel_launch(void* const* d_in, const int* in_sizes, int n_in,
                              void* d_out, int out_size, void* d_ws, size_t ws_size,
                              hipStream_t stream) {
  (void)in_sizes; (void)n_in; (void)out_size; (void)ws_size;
  const float* Zs = (const float*)d_in[0];
  const int*   Ys = (const int*)d_in[1];
  const float* Zq = (const float*)d_in[2];
  const float* log_ls = (const float*)d_in[3];
  const float* log_noise = (const float*)d_in[4];
  float* out = (float*)d_out;

  float* ws = (float*)d_ws;
  float* K  = ws;                                     // 512*512 f32
  float* sn = ws + (size_t)NS * NS;                   // 512 f32
  unsigned short* alpha_t = (unsigned short*)(sn + NS);      // [16][512] bf16 (4096 f32 slots)
  float* Wg = sn + NS + 4096;                         // [512][16] f32
  int* flags = (int*)(Wg + (size_t)NS * NW);          // {cnt, gen}

  hipMemsetAsync(flags, 0, 2 * sizeof(int), stream);
  setup_all<<<NWG, 256, 0, stream>>>(Zs, Ys, log_ls, log_noise, K, sn, Wg, alpha_t,
                                     flags, flags + 1);
  fused_v2<<<NQ / 128, 512, 0, stream>>>(Zq, Zs, sn, alpha_t, log_ls, out);
}

// Round 8
// 1707.980 us; speedup vs baseline: 1.3875x; 1.3875x over previous
//
#include <hip/hip_runtime.h>
#include <math.h>

#define NS 512      // N_way*K_shot support samples
#define NQ 65536    // N_way*Q_query rows
#define DD 1024     // feature dim
#define NW 16       // N_way
#define NWG 36      // setup kernel workgroups (<< 256 CUs -> co-resident)

typedef __attribute__((ext_vector_type(8))) short short8x;
typedef __attribute__((ext_vector_type(4))) float floatx4;

static __device__ __forceinline__ unsigned short bf_trunc(float x) {
  return (unsigned short)(__float_as_uint(x) >> 16);
}
static __device__ __forceinline__ float bf_tof(unsigned short h) {
  return __uint_as_float(((unsigned)h) << 16);
}
static __device__ __forceinline__ unsigned short bf_rne(float x) {
  unsigned u = __float_as_uint(x);
  return (unsigned short)((u + 0x7FFFu + ((u >> 16) & 1u)) >> 16);
}

// split f32 -> (hi, lo) bf16 pair, swizzled 8B LDS store. k0 multiple of 4.
#define STASH(Hp, Lp, row, k0, v) do {                                      \
    unsigned e_ = (unsigned)((((row) * 32 + (k0)) ^ (((row) & 7) << 3)));   \
    ushort4 h_, l_;                                                         \
    h_.x = bf_trunc((v).x); l_.x = bf_trunc((v).x - bf_tof(h_.x));          \
    h_.y = bf_trunc((v).y); l_.y = bf_trunc((v).y - bf_tof(h_.y));          \
    h_.z = bf_trunc((v).z); l_.z = bf_trunc((v).z - bf_tof(h_.z));          \
    h_.w = bf_trunc((v).w); l_.w = bf_trunc((v).w - bf_tof(h_.w));          \
    *(ushort4*)&Hp[e_] = h_; *(ushort4*)&Lp[e_] = l_;                       \
  } while (0)

// ---------------- device-wide barrier (36 co-resident WGs) ----------------
// Key: poll with RELAXED (no per-poll L2 invalidate); pay release fence once
// before arrival and acquire fence once after exit. Last arriver resets cnt
// then publishes gen with RELEASE (orders reset before publication).
__device__ __forceinline__ void gbar(int* cnt, int* gen) {
  __syncthreads();
  if (threadIdx.x == 0) {
    int g = __hip_atomic_load(gen, __ATOMIC_RELAXED, __HIP_MEMORY_SCOPE_AGENT);
    __threadfence();  // release: this WG's writes -> device visible (L2 wb)
    int p = __hip_atomic_fetch_add(cnt, 1, __ATOMIC_RELAXED, __HIP_MEMORY_SCOPE_AGENT);
    if (p == NWG - 1) {
      __hip_atomic_store(cnt, 0, __ATOMIC_RELAXED, __HIP_MEMORY_SCOPE_AGENT);
      __hip_atomic_store(gen, g + 1, __ATOMIC_RELEASE, __HIP_MEMORY_SCOPE_AGENT);
    } else {
      while (__hip_atomic_load(gen, __ATOMIC_RELAXED, __HIP_MEMORY_SCOPE_AGENT) == g)
        __builtin_amdgcn_s_sleep(4);
    }
    __threadfence();  // acquire: invalidate caches before next phase's loads
  }
  __syncthreads();
}

// wave-0 register potrf of a 64x64 tile staged in LDS (stride 68);
// writes L (lower+diag) and its transpose mirror to K at panel offset j.
__device__ __forceinline__ void potrf_tile(const float* T68, float* __restrict__ K, int j) {
  const int tid = threadIdx.x;
  if (tid < 64) {
    const int r = tid;
    float ar[64];
    #pragma unroll
    for (int c4 = 0; c4 < 16; ++c4)
      *(floatx4*)&ar[c4 * 4] = *(const floatx4*)&T68[r * 68 + c4 * 4];
    #pragma unroll
    for (int c = 0; c < 64; ++c) {
      float colv = ar[c];
      float d = __shfl(colv, c);
      float sq = sqrtf(d);
      float inv = 1.f / sq;
      float x = (r > c) ? colv * inv : ((r == c) ? sq : 0.f);
      ar[c] = x;
      #pragma unroll
      for (int k = c + 1; k < 64; ++k) {
        float xk = __shfl(x, k);
        ar[k] = fmaf(-x, xk, ar[k]);   // junk in upper region, never read
      }
    }
    #pragma unroll
    for (int c = 0; c < 64; ++c) {
      if (c <= r) K[(size_t)(j + r) * NS + j + c] = ar[c];
      if (c < r)  K[(size_t)(j + c) * NS + j + r] = ar[c];   // mirror
    }
  }
}

// wave-0 lockstep lower-triangular solve of 64x16 block (validated r4 logic).
// P: LDS diag tile (stride 68, lower=L). Writes WsT (LDS, stride 68) + Wg.
__device__ __forceinline__ void solve_lower(const float* P, const float* invd,
                                            const float* __restrict__ Wsrc16,
                                            float* WsT, float* __restrict__ Wg, int j) {
  const int tid = threadIdx.x;
  if (tid < 64) {
    const int n = tid & 15, rq = tid >> 4;
    float w16[16];
    #pragma unroll
    for (int i = 0; i < 16; ++i) w16[i] = Wsrc16[(size_t)(rq + 4 * i) * 16 + n];
    #pragma unroll
    for (int g = 0; g < 16; ++g) {
      floatx4 p[16];
      #pragma unroll
      for (int i = 0; i < 16; ++i) p[i] = *(const floatx4*)&P[(rq + 4 * i) * 68 + 4 * g];
      #pragma unroll
      for (int cj = 0; cj < 4; ++cj) {
        const int c = 4 * g + cj;
        float xc = __shfl(w16[c >> 2], ((c & 3) << 4) + n) * invd[c];
        if (rq == (c & 3)) w16[c >> 2] = xc;
        #pragma unroll
        for (int i = 0; i < 16; ++i) {
          int r = rq + 4 * i;
          if (r > c) w16[i] -= p[i][cj] * xc;
        }
      }
    }
    #pragma unroll
    for (int i = 0; i < 16; ++i) {
      WsT[n * 68 + rq + 4 * i] = w16[i];
      Wg[(size_t)(j + rq + 4 * i) * 16 + n] = w16[i];
    }
  }
}

// wave-0 lockstep upper-triangular solve (L^T) of 64x16 block (validated r4).
// P upper triangle = L^T mirror. Reads Wsrc16 (global), writes Wg.
__device__ __forceinline__ void solve_upper(const float* P, const float* invd,
                                            const float* __restrict__ Wsrc16,
                                            float* __restrict__ Wg, int j) {
  const int tid = threadIdx.x;
  if (tid < 64) {
    const int n = tid & 15, rq = tid >> 4;
    float w16[16];
    #pragma unroll
    for (int i = 0; i < 16; ++i) w16[i] = Wsrc16[(size_t)(rq + 4 * i) * 16 + n];
    #pragma unroll
    for (int g = 15; g >= 0; --g) {
      floatx4 p[16];
      #pragma unroll
      for (int i = 0; i < 16; ++i) p[i] = *(const floatx4*)&P[(rq + 4 * i) * 68 + 4 * g];
      #pragma unroll
      for (int cj = 3; cj >= 0; --cj) {
        const int c = 4 * g + cj;
        float xc = __shfl(w16[c >> 2], ((c & 3) << 4) + n) * invd[c];
        if (rq == (c & 3)) w16[c >> 2] = xc;
        #pragma unroll
        for (int i = 0; i < 16; ++i) {
          int r = rq + 4 * i;
          if (r < c) w16[i] -= p[i][cj] * xc;
        }
      }
    }
    #pragma unroll
    for (int i = 0; i < 16; ++i)
      Wg[(size_t)(j + rq + 4 * i) * 16 + n] = w16[i];
  }
}

// ==================== one-launch setup: norms + Kss + Cholesky + solve ====================
__global__ __launch_bounds__(256) void setup_all(const float* __restrict__ Zs,
                                                 const int* __restrict__ Ys,
                                                 const float* __restrict__ log_ls,
                                                 const float* __restrict__ log_noise,
                                                 float* __restrict__ K,
                                                 float* __restrict__ sn,
                                                 float* __restrict__ Wg,
                                                 unsigned short* __restrict__ alpha_t,
                                                 int* cnt, int* gen) {
  __shared__ float pf[13184];   // 52.7 KB pool, phase-aliased
  const int wg = blockIdx.x, tid = threadIdx.x;

  // ---- phase 0: Zs row norms + W one-hot init ----
  {
    int wave = tid >> 6, lane = tid & 63;
    for (int r = wg * 4 + wave; r < NS; r += NWG * 4) {
      const float* row = Zs + (size_t)r * DD;
      float s = 0.f;
      #pragma unroll
      for (int i = 0; i < 4; ++i) {
        float4 v = *(const float4*)(row + 4 * lane + 256 * i);
        s += v.x * v.x + v.y * v.y + v.z * v.z + v.w * v.w;
      }
      #pragma unroll
      for (int off = 32; off; off >>= 1) s += __shfl_xor(s, off);
      if (lane == 0) sn[r] = s;
    }
    int flat = wg * 256 + tid;
    if (flat < NS * NW) Wg[flat] = (Ys[flat >> 4] == (flat & 15)) ? 1.f : 0.f;
  }
  gbar(cnt, gen);

  // ---- phase K: Kss lower-tri tiles (1 per WG, 36 tiles) + potrf(0) on WG0 ----
  {
    int by = 0, accv = 0;
    while (accv + by + 1 <= wg) { accv += by + 1; ++by; }
    int bx = wg - accv;
    const int rb = by * 64, cb = bx * 64;
    float* At = pf;             // [16][68]
    float* Bt = pf + 1088;      // [16][68]
    float* Tile = pf + 8832;    // [64][68] (WG0 potrf hand-off)
    const int tx = tid & 15, ty = tid >> 4;
    const int srow = tid & 63, skq = (tid >> 6) << 2;
    float acc[4][4] = {};
    for (int kk = 0; kk < DD; kk += 16) {
      __syncthreads();
      float4 a = *(const float4*)(Zs + (size_t)(rb + srow) * DD + kk + skq);
      float4 b = *(const float4*)(Zs + (size_t)(cb + srow) * DD + kk + skq);
      At[(skq + 0) * 68 + srow] = a.x; At[(skq + 1) * 68 + srow] = a.y;
      At[(skq + 2) * 68 + srow] = a.z; At[(skq + 3) * 68 + srow] = a.w;
      Bt[(skq + 0) * 68 + srow] = b.x; Bt[(skq + 1) * 68 + srow] = b.y;
      Bt[(skq + 2) * 68 + srow] = b.z; Bt[(skq + 3) * 68 + srow] = b.w;
      __syncthreads();
      #pragma unroll
      for (int k = 0; k < 16; ++k) {
        floatx4 av = *(const floatx4*)&At[k * 68 + ty * 4];
        floatx4 bv = *(const floatx4*)&Bt[k * 68 + tx * 4];
        #pragma unroll
        for (int i = 0; i < 4; ++i)
          #pragma unroll
          for (int jj = 0; jj < 4; ++jj)
            acc[i][jj] = fmaf(av[i], bv[jj], acc[i][jj]);
      }
    }
    float inv2 = 0.5f * expf(-2.f * log_ls[0]);
    float noise = expf(2.f * log_noise[0]);
    #pragma unroll
    for (int i = 0; i < 4; ++i)
      #pragma unroll
      for (int jj = 0; jj < 4; ++jj) {
        int r = rb + ty * 4 + i, c = cb + tx * 4 + jj;
        float d2 = fmaxf(sn[r] + sn[c] - 2.f * acc[i][jj], 0.f);
        float v = expf(-d2 * inv2);
        if (r == c) v += noise;
        K[(size_t)r * NS + c] = v;
        if (wg == 0) Tile[(ty * 4 + i) * 68 + tx * 4 + jj] = v;
      }
    if (wg == 0) {
      __syncthreads();
      potrf_tile(Tile, K, 0);
    }
  }
  gbar(cnt, gen);

  // ---- Cholesky panels jb=0..6: trsm phase / [syrk + potrf(jb+1) + fwd-solve(jb)] phase ----
  for (int jb = 0; jb < 7; ++jb) {
    const int j = jb << 6;
    // --- phase T: trsm rows below panel jb (rows interleaved across WGs) ---
    {
      float* Ld = pf;            // [64][68]
      float* invd = pf + 4416;   // [64]
      #pragma unroll
      for (int it = 0; it < 4; ++it) {
        int flat = tid + 256 * it;
        int r = flat >> 4, c4 = (flat & 15) * 4;
        *(floatx4*)&Ld[r * 68 + c4] = *(const floatx4*)&K[(size_t)(j + r) * NS + j + c4];
      }
      __syncthreads();
      if (tid < 64) invd[tid] = 1.f / Ld[tid * 68 + tid];
      __syncthreads();
      const int r0 = j + 64 + wg + NWG * tid;
      if (r0 < NS) {
        float xr[64];
        #pragma unroll
        for (int c4 = 0; c4 < 16; ++c4)
          *(floatx4*)&xr[c4 * 4] = *(const floatx4*)&K[(size_t)r0 * NS + j + c4 * 4];
        #pragma unroll
        for (int g = 0; g < 16; ++g) {
          float v0 = xr[4 * g], v1 = xr[4 * g + 1], v2 = xr[4 * g + 2], v3 = xr[4 * g + 3];
          for (int kb = 0; kb < g; ++kb) {
            floatx4 x4 = *(const floatx4*)&xr[4 * kb];
            floatx4 l0 = *(const floatx4*)&Ld[(4 * g + 0) * 68 + 4 * kb];
            floatx4 l1 = *(const floatx4*)&Ld[(4 * g + 1) * 68 + 4 * kb];
            floatx4 l2 = *(const floatx4*)&Ld[(4 * g + 2) * 68 + 4 * kb];
            floatx4 l3 = *(const floatx4*)&Ld[(4 * g + 3) * 68 + 4 * kb];
            v0 -= x4.x * l0.x + x4.y * l0.y + x4.z * l0.z + x4.w * l0.w;
            v1 -= x4.x * l1.x + x4.y * l1.y + x4.z * l1.z + x4.w * l1.w;
            v2 -= x4.x * l2.x + x4.y * l2.y + x4.z * l2.z + x4.w * l2.w;
            v3 -= x4.x * l3.x + x4.y * l3.y + x4.z * l3.z + x4.w * l3.w;
          }
          const int c0 = 4 * g;
          float x0 = v0 * invd[c0];
          v1 -= x0 * Ld[(c0 + 1) * 68 + c0];
          float x1 = v1 * invd[c0 + 1];
          v2 -= x0 * Ld[(c0 + 2) * 68 + c0] + x1 * Ld[(c0 + 2) * 68 + c0 + 1];
          float x2 = v2 * invd[c0 + 2];
          v3 -= x0 * Ld[(c0 + 3) * 68 + c0] + x1 * Ld[(c0 + 3) * 68 + c0 + 1] + x2 * Ld[(c0 + 3) * 68 + c0 + 2];
          float x3 = v3 * invd[c0 + 3];
          xr[c0] = x0; xr[c0 + 1] = x1; xr[c0 + 2] = x2; xr[c0 + 3] = x3;
        }
        #pragma unroll
        for (int c4 = 0; c4 < 16; ++c4)
          *(floatx4*)(K + (size_t)r0 * NS + j + c4 * 4) = *(const floatx4*)&xr[c4 * 4];
        #pragma unroll
        for (int c = 0; c < 64; ++c)
          K[(size_t)(j + c) * NS + r0] = xr[c];   // mirror (L^T)
      }
    }
    gbar(cnt, gen);

    // --- phase S: syrk trailing tiles (WG<nt); WG0 also potrf(jb+1); WG35 fwd-solve(jb) ---
    {
      const int T = 7 - jb;
      const int nt = T * (T + 1) / 2;
      if (wg < nt) {
        int ti = 0, a2 = 0;
        while (a2 + ti + 1 <= wg) { a2 += ti + 1; ++ti; }
        int tj = wg - a2;
        const int rbt = j + 64 + ti * 64, cbt = j + 64 + tj * 64;
        float* A = pf;            // [64][69]
        float* B = pf + 4416;     // [64][69]
        float* Tile = pf + 8832;  // [64][68] (WG0 only)
        for (int i = tid; i < 4096; i += 256) {
          int r = i >> 6, k = i & 63;
          A[r * 69 + k] = K[(size_t)(rbt + r) * NS + j + k];
          B[r * 69 + k] = K[(size_t)(cbt + r) * NS + j + k];
        }
        __syncthreads();
        const int tx = tid & 15, ty = tid >> 4;
        float acc[4][4] = {};
        for (int k = 0; k < 64; ++k) {
          float aa[4], bb[4];
          #pragma unroll
          for (int i = 0; i < 4; ++i) aa[i] = A[(ty * 4 + i) * 69 + k];
          #pragma unroll
          for (int i = 0; i < 4; ++i) bb[i] = B[(tx * 4 + i) * 69 + k];
          #pragma unroll
          for (int i = 0; i < 4; ++i)
            #pragma unroll
            for (int jj = 0; jj < 4; ++jj)
              acc[i][jj] = fmaf(aa[i], bb[jj], acc[i][jj]);
        }
        #pragma unroll
        for (int i = 0; i < 4; ++i)
          #pragma unroll
          for (int jj = 0; jj < 4; ++jj) {
            float* cp = &K[(size_t)(rbt + ty * 4 + i) * NS + cbt + tx * 4 + jj];
            float nv = *cp - acc[i][jj];
            *cp = nv;
            if (wg == 0) Tile[(ty * 4 + i) * 68 + tx * 4 + jj] = nv;
          }
        if (wg == 0) {
          __syncthreads();
          potrf_tile(Tile, K, j + 64);
        }
      } else if (wg == 35) {
        // forward solve of W block jb + rank-64 update of all rows below
        float* P = pf;            // [64][68]
        float* invd = pf + 4416;  // [64]
        float* WsT = pf + 5504;   // [16][68]
        #pragma unroll
        for (int it = 0; it < 4; ++it) {
          int flat = tid + 256 * it;
          int r = flat >> 4, c4 = (flat & 15) * 4;
          *(floatx4*)&P[r * 68 + c4] = *(const floatx4*)&K[(size_t)(j + r) * NS + j + c4];
        }
        __syncthreads();
        if (tid < 64) invd[tid] = 1.f / P[tid * 68 + tid];
        solve_lower(P, invd, Wg + (size_t)j * 16, WsT, Wg, j);
        __syncthreads();
        const int nrows = NS - j - 64;
        for (int flat = tid; flat < nrows * 16; flat += 256) {
          int row = j + 64 + (flat >> 4), nn = flat & 15;
          float s = Wg[(size_t)row * 16 + nn];
          const float* lrow = &K[(size_t)row * NS + j];
          #pragma unroll
          for (int g = 0; g < 16; ++g) {
            floatx4 lv = *(const floatx4*)&lrow[4 * g];
            floatx4 wv = *(const floatx4*)&WsT[nn * 68 + 4 * g];
            s -= lv.x * wv.x + lv.y * wv.y + lv.z * wv.z + lv.w * wv.w;
          }
          Wg[(size_t)row * 16 + nn] = s;
        }
      }
    }
    gbar(cnt, gen);
  }

  // ---- phase X7: forward+backward solve of block 7 (WG35) ----
  {
    const int j = 448;
    if (wg == 35) {
      float* P = pf;
      float* invd = pf + 4416;
      float* WsT = pf + 5504;
      #pragma unroll
      for (int it = 0; it < 4; ++it) {
        int flat = tid + 256 * it;
        int r = flat >> 4, c4 = (flat & 15) * 4;
        *(floatx4*)&P[r * 68 + c4] = *(const floatx4*)&K[(size_t)(j + r) * NS + j + c4];
      }
      __syncthreads();
      if (tid < 64) invd[tid] = 1.f / P[tid * 68 + tid];
      solve_lower(P, invd, Wg + (size_t)j * 16, WsT, Wg, j);
      // same wave continues: upper solve reads its own Wg writes
      solve_upper(P, invd, Wg + (size_t)j * 16, Wg, j);
    }
  }
  gbar(cnt, gen);

  // ---- backward: BU(jb) update rows above, then BD(jb-1) solve; jb = 7..1 ----
  for (int jb = 7; jb >= 1; --jb) {
    const int j = jb << 6;
    // --- BU(jb): all WGs update rows r < j with solved block jb ---
    {
      float* Wst = pf;   // [16][68] transposed block
      for (int e = tid; e < 1024; e += 256) {
        int c = e >> 4, n = e & 15;
        Wst[n * 68 + c] = Wg[(size_t)(j + c) * 16 + n];
      }
      __syncthreads();
      const int row = wg + NWG * (tid >> 4);
      const int nn = tid & 15;
      if (row < j) {
        float s = Wg[(size_t)row * 16 + nn];
        const float* lrow = &K[(size_t)row * NS + j];   // upper mirror = L^T
        #pragma unroll
        for (int g = 0; g < 16; ++g) {
          floatx4 lv = *(const floatx4*)&lrow[4 * g];
          floatx4 wv = *(const floatx4*)&Wst[nn * 68 + 4 * g];
          s -= lv.x * wv.x + lv.y * wv.y + lv.z * wv.z + lv.w * wv.w;
        }
        Wg[(size_t)row * 16 + nn] = s;
      }
    }
    gbar(cnt, gen);
    // --- BD(jb-1): WG35 upper-solve block jb-1 ---
    {
      const int j2 = (jb - 1) << 6;
      if (wg == 35) {
        float* P = pf;
        float* invd = pf + 4416;
        #pragma unroll
        for (int it = 0; it < 4; ++it) {
          int flat = tid + 256 * it;
          int r = flat >> 4, c4 = (flat & 15) * 4;
          *(floatx4*)&P[r * 68 + c4] = *(const floatx4*)&K[(size_t)(j2 + r) * NS + j2 + c4];
        }
        __syncthreads();
        if (tid < 64) invd[tid] = 1.f / P[tid * 68 + tid];
        solve_upper(P, invd, Wg + (size_t)j2 * 16, Wg, j2);
      }
    }
    gbar(cnt, gen);
  }

  // ---- final: alpha_t = bf16(W)^T ----
  {
    int flat = wg * 256 + tid;
    if (flat < NS * NW) {
      int r = flat >> 4, nn = flat & 15;
      alpha_t[(size_t)nn * NS + r] = bf_rne(Wg[(size_t)r * 16 + nn]);
    }
  }
}

// ---------------- fused: split-bf16 MFMA Gram -> exp -> MFMA PV -> softmax ----------------
__global__ __launch_bounds__(512) void fused_v2(const float* __restrict__ Zq,
                                                const float* __restrict__ Zs,
                                                const float* __restrict__ sn,
                                                const unsigned short* __restrict__ alpha_t,
                                                const float* __restrict__ log_ls,
                                                float* __restrict__ out) {
  __shared__ __align__(16) unsigned short LB[32768];  // 64 KB, unioned
  __shared__ float qnl[128];
  __shared__ float snl[256];
  unsigned short* AhB = LB;            // Zq hi  [128][32]
  unsigned short* AlB = LB + 4096;     // Zq lo
  unsigned short* BhB = LB + 8192;     // Zs hi  [256][32]
  unsigned short* BlB = LB + 16384;    // Zs lo
  unsigned short* KqB = LB;            // Kq bf16 [128][256] (epilogue overlay)

  const int tid = threadIdx.x;
  const int lane = tid & 63;
  const int w = tid >> 6;              // 8 waves: 2(m) x 4(n)
  const int wm = w >> 2, wn = w & 3;
  const int l15 = lane & 15, l4 = lane >> 4;
  const int rb = blockIdx.x * 128;
  const float inv2 = 0.5f * __expf(-2.f * log_ls[0]);
  const unsigned swz = (unsigned)((l15 & 7) << 3);

  if (tid < 128) qnl[tid] = 0.f;
  __syncthreads();

  const int qrow0 = tid >> 3;          // 0..63
  const int qk0 = (tid & 7) * 4;
  const int qrow1 = 64 + qrow0;

  floatx4 facc = {0.f, 0.f, 0.f, 0.f};

  for (int cc = 0; cc < NS; cc += 256) {
    if (tid < 256) snl[tid] = sn[cc + tid];
    floatx4 acc[4][4];
    #pragma unroll
    for (int a = 0; a < 4; ++a)
      #pragma unroll
      for (int b = 0; b < 4; ++b) acc[a][b] = (floatx4){0.f, 0.f, 0.f, 0.f};

    // prefetch kt = 0
    float4 pq0 = *(const float4*)(Zq + (size_t)(rb + qrow0) * DD + qk0);
    float4 pq1 = *(const float4*)(Zq + (size_t)(rb + qrow1) * DD + qk0);
    float4 ps[4];
    #pragma unroll
    for (int u = 0; u < 4; ++u) {
      int idx = tid + (u << 9);
      ps[u] = *(const float4*)(Zs + (size_t)(cc + (idx >> 3)) * DD + ((idx & 7) * 4));
    }

    for (int kt = 0; kt < 32; ++kt) {
      // ---- STORE phase: regs -> swizzled split-bf16 LDS ----
      STASH(AhB, AlB, qrow0, qk0, pq0);
      STASH(AhB, AlB, qrow1, qk0, pq1);
      #pragma unroll
      for (int u = 0; u < 4; ++u) {
        int idx = tid + (u << 9);
        int srow = idx >> 3, sk0 = (idx & 7) * 4;
        STASH(BhB, BlB, srow, sk0, ps[u]);
      }
      if (cc == 0) {  // fold Zq row-norm accumulation into chunk-0 staging
        float s0 = pq0.x * pq0.x + pq0.y * pq0.y + pq0.z * pq0.z + pq0.w * pq0.w;
        float s1 = pq1.x * pq1.x + pq1.y * pq1.y + pq1.z * pq1.z + pq1.w * pq1.w;
        #pragma unroll
        for (int d = 1; d < 8; d <<= 1) { s0 += __shfl_xor(s0, d); s1 += __shfl_xor(s1, d); }
        if ((tid & 7) == 0) { qnl[qrow0] += s0; qnl[qrow1] += s1; }
      }
      __syncthreads();
      // ---- prefetch next iter (hidden under MFMA) ----
      if (kt < 31) {
        int kk2 = (kt + 1) << 5;
        pq0 = *(const float4*)(Zq + (size_t)(rb + qrow0) * DD + kk2 + qk0);
        pq1 = *(const float4*)(Zq + (size_t)(rb + qrow1) * DD + kk2 + qk0);
        #pragma unroll
        for (int u = 0; u < 4; ++u) {
          int idx = tid + (u << 9);
          ps[u] = *(const float4*)(Zs + (size_t)(cc + (idx >> 3)) * DD + kk2 + ((idx & 7) * 4));
        }
      }
      // ---- compute: 16 ds_read_b128 + 48 MFMA ----
      short8x ah[4], al[4], bh[4], bl[4];
      #pragma unroll
      for (int mi = 0; mi < 4; ++mi) {
        unsigned e = (unsigned)((wm * 64 + mi * 16 + l15) * 32 + 8 * l4) ^ swz;
        ah[mi] = *(const short8x*)&AhB[e];
        al[mi] = *(const short8x*)&AlB[e];
      }
      #pragma unroll
      for (int ni = 0; ni < 4; ++ni) {
        unsigned e = (unsigned)((wn * 64 + ni * 16 + l15) * 32 + 8 * l4) ^ swz;
        bh[ni] = *(const short8x*)&BhB[e];
        bl[ni] = *(const short8x*)&BlB[e];
      }
      #pragma unroll
      for (int mi = 0; mi < 4; ++mi)
        #pragma unroll
        for (int ni = 0; ni < 4; ++ni) {
          acc[mi][ni] = __builtin_amdgcn_mfma_f32_16x16x32_bf16(ah[mi], bh[ni], acc[mi][ni], 0, 0, 0);
          acc[mi][ni] = __builtin_amdgcn_mfma_f32_16x16x32_bf16(ah[mi], bl[ni], acc[mi][ni], 0, 0, 0);
          acc[mi][ni] = __builtin_amdgcn_mfma_f32_16x16x32_bf16(al[mi], bh[ni], acc[mi][ni], 0, 0, 0);
        }
      __syncthreads();
    }

    // ---- epilogue: PV B-frags (alpha^T, global/L2), kq -> KqB, PV MFMA ----
    short8x bfr[8];
    #pragma unroll
    for (int s = 0; s < 8; ++s)
      bfr[s] = *(const short8x*)(alpha_t + ((size_t)l15 * NS + cc + 32 * s + 8 * l4));

    #pragma unroll
    for (int mi = 0; mi < 4; ++mi)
      #pragma unroll
      for (int rr = 0; rr < 4; ++rr) {
        int row_l = wm * 64 + mi * 16 + l4 * 4 + rr;
        float qv = qnl[row_l];
        unsigned sw = (unsigned)((row_l & 7) << 3);
        #pragma unroll
        for (int ni = 0; ni < 4; ++ni) {
          int col = wn * 64 + ni * 16 + l15;
          float d2 = fmaxf(qv + snl[col] - 2.f * acc[mi][ni][rr], 0.f);
          float kq = __expf(-d2 * inv2);
          KqB[(unsigned)(row_l * 256 + col) ^ sw] = bf_rne(kq);
        }
      }
    __syncthreads();
    #pragma unroll
    for (int s = 0; s < 8; ++s) {
      unsigned e = (unsigned)((w * 16 + l15) * 256 + 32 * s + 8 * l4) ^ swz;
      short8x ak = *(const short8x*)&KqB[e];
      facc = __builtin_amdgcn_mfma_f32_16x16x32_bf16(ak, bfr[s], facc, 0, 0, 0);
    }
    __syncthreads();
  }

  // ---- softmax over 16 classes (spread across 16-lane groups) ----
  #pragma unroll
  for (int r = 0; r < 4; ++r) {
    float v = facc[r];
    float m = v;
    #pragma unroll
    for (int d = 1; d < 16; d <<= 1) m = fmaxf(m, __shfl_xor(m, d));
    float e = __expf(v - m);
    float s = e;
    #pragma unroll
    for (int d = 1; d < 16; d <<= 1) s += __shfl_xor(s, d);
    out[(size_t)(rb + w * 16 + l4 * 4 + r) * NW + l15] = e / s;
  }
}

extern "C" void kernel_launch(void* const* d_in, const int* in_sizes, int n_in,
                              void* d_out, int out_size, void* d_ws, size_t ws_size,
                              hipStream_t stream) {
  (void)in_sizes; (void)n_in; (void)out_size; (void)ws_size;
  const float* Zs = (const float*)d_in[0];
  const int*   Ys = (const int*)d_in[1];
  const float* Zq = (const float*)d_in[2];
  const float* log_ls = (const float*)d_in[3];
  const float* log_noise = (const float*)d_in[4];
  float* out = (float*)d_out;

  float* ws = (float*)d_ws;
  float* K  = ws;                                     // 512*512 f32
  float* sn = ws + (size_t)NS * NS;                   // 512 f32
  unsigned short* alpha_t = (unsigned short*)(sn + NS);      // [16][512] bf16 (4096 f32 slots)
  float* Wg = sn + NS + 4096;                         // [512][16] f32
  int* flags = (int*)(Wg + (size_t)NS * NW);          // {cnt, gen}

  hipMemsetAsync(flags, 0, 2 * sizeof(int), stream);
  setup_all<<<NWG, 256, 0, stream>>>(Zs, Ys, log_ls, log_noise, K, sn, Wg, alpha_t,
                                     flags, flags + 1);
  fused_v2<<<NQ / 128, 512, 0, stream>>>(Zq, Zs, sn, alpha_t, log_ls, out);
}

// Round 11
// 1663.384 us; speedup vs baseline: 1.4247x; 1.0268x over previous
//
#include <hip/hip_runtime.h>
#include <math.h>

#define NS 512
#define NQ 65536
#define DD 1024
#define NW 16
#define NWG 36

typedef __attribute__((ext_vector_type(8))) short short8x;
typedef __attribute__((ext_vector_type(4))) float floatx4;

static __device__ __forceinline__ unsigned short bf_trunc(float x) {
  return (unsigned short)(__float_as_uint(x) >> 16);
}
static __device__ __forceinline__ float bf_tof(unsigned short h) {
  return __uint_as_float(((unsigned)h) << 16);
}
static __device__ __forceinline__ unsigned short bf_rne(float x) {
  unsigned u = __float_as_uint(x);
  return (unsigned short)((u + 0x7FFFu + ((u >> 16) & 1u)) >> 16);
}

// split f32 -> (hi, lo) bf16 pair, swizzled 8B LDS store. k0 multiple of 4.
#define STASH(Hp, Lp, row, k0, v) do {                                      \
    unsigned e_ = (unsigned)((((row) * 32 + (k0)) ^ (((row) & 7) << 3)));   \
    ushort4 h_, l_;                                                         \
    h_.x = bf_trunc((v).x); l_.x = bf_trunc((v).x - bf_tof(h_.x));          \
    h_.y = bf_trunc((v).y); l_.y = bf_trunc((v).y - bf_tof(h_.y));          \
    h_.z = bf_trunc((v).z); l_.z = bf_trunc((v).z - bf_tof(h_.z));          \
    h_.w = bf_trunc((v).w); l_.w = bf_trunc((v).w - bf_tof(h_.w));          \
    *(ushort4*)&Hp[e_] = h_; *(ushort4*)&Lp[e_] = l_;                       \
  } while (0)

// device-wide barrier (relaxed poll; fences at entry/exit only)
__device__ __forceinline__ void gbar(int* cnt, int* gen) {
  __syncthreads();
  if (threadIdx.x == 0) {
    int g = __hip_atomic_load(gen, __ATOMIC_RELAXED, __HIP_MEMORY_SCOPE_AGENT);
    __threadfence();
    int p = __hip_atomic_fetch_add(cnt, 1, __ATOMIC_RELAXED, __HIP_MEMORY_SCOPE_AGENT);
    if (p == NWG - 1) {
      __hip_atomic_store(cnt, 0, __ATOMIC_RELAXED, __HIP_MEMORY_SCOPE_AGENT);
      __hip_atomic_store(gen, g + 1, __ATOMIC_RELEASE, __HIP_MEMORY_SCOPE_AGENT);
    } else {
      while (__hip_atomic_load(gen, __ATOMIC_RELAXED, __HIP_MEMORY_SCOPE_AGENT) == g)
        __builtin_amdgcn_s_sleep(4);
    }
    __threadfence();
  }
  __syncthreads();
}

// wave-0 register potrf of a 64x64 tile in LDS (stride 68); writes L + mirror to K diag.
__device__ __forceinline__ void potrf_tile(const float* T68, float* __restrict__ K, int j) {
  const int tid = threadIdx.x;
  if (tid < 64) {
    const int r = tid;
    float ar[64];
    #pragma unroll
    for (int c4 = 0; c4 < 16; ++c4)
      *(floatx4*)&ar[c4 * 4] = *(const floatx4*)&T68[r * 68 + c4 * 4];
    #pragma unroll
    for (int c = 0; c < 64; ++c) {
      float colv = ar[c];
      float d = __shfl(colv, c);
      float sq = sqrtf(d);
      float inv = 1.f / sq;
      float x = (r > c) ? colv * inv : ((r == c) ? sq : 0.f);
      ar[c] = x;
      #pragma unroll
      for (int k = c + 1; k < 64; ++k) {
        float xk = __shfl(x, k);
        ar[k] = fmaf(-x, xk, ar[k]);
      }
    }
    #pragma unroll
    for (int c = 0; c < 64; ++c) {
      if (c <= r) K[(size_t)(j + r) * NS + j + c] = ar[c];
      if (c < r)  K[(size_t)(j + c) * NS + j + r] = ar[c];
    }
  }
}

// solve xr * L11^T = Krow (Ld = LDS diag panel stride 68, lower = L)
__device__ __forceinline__ void trsm_row(const float* __restrict__ Krow,
                                         const float* Ld, const float* invd,
                                         float* xr) {
  #pragma unroll
  for (int c4 = 0; c4 < 16; ++c4)
    *(floatx4*)&xr[c4 * 4] = *(const floatx4*)(Krow + c4 * 4);
  #pragma unroll
  for (int g = 0; g < 16; ++g) {
    float v0 = xr[4 * g + 0], v1 = xr[4 * g + 1], v2 = xr[4 * g + 2], v3 = xr[4 * g + 3];
    for (int kb = 0; kb < g; ++kb) {
      floatx4 x4 = *(const floatx4*)&xr[4 * kb];
      floatx4 l0 = *(const floatx4*)&Ld[(4 * g + 0) * 68 + 4 * kb];
      floatx4 l1 = *(const floatx4*)&Ld[(4 * g + 1) * 68 + 4 * kb];
      floatx4 l2 = *(const floatx4*)&Ld[(4 * g + 2) * 68 + 4 * kb];
      floatx4 l3 = *(const floatx4*)&Ld[(4 * g + 3) * 68 + 4 * kb];
      v0 -= x4.x * l0.x + x4.y * l0.y + x4.z * l0.z + x4.w * l0.w;
      v1 -= x4.x * l1.x + x4.y * l1.y + x4.z * l1.z + x4.w * l1.w;
      v2 -= x4.x * l2.x + x4.y * l2.y + x4.z * l2.z + x4.w * l2.w;
      v3 -= x4.x * l3.x + x4.y * l3.y + x4.z * l3.z + x4.w * l3.w;
    }
    const int c0 = 4 * g;
    float x0 = v0 * invd[c0];
    v1 -= x0 * Ld[(c0 + 1) * 68 + c0];
    float x1 = v1 * invd[c0 + 1];
    v2 -= x0 * Ld[(c0 + 2) * 68 + c0] + x1 * Ld[(c0 + 2) * 68 + c0 + 1];
    float x2 = v2 * invd[c0 + 2];
    v3 -= x0 * Ld[(c0 + 3) * 68 + c0] + x1 * Ld[(c0 + 3) * 68 + c0 + 1] + x2 * Ld[(c0 + 3) * 68 + c0 + 2];
    float x3 = v3 * invd[c0 + 3];
    xr[c0] = x0; xr[c0 + 1] = x1; xr[c0 + 2] = x2; xr[c0 + 3] = x3;
  }
}

// wave-0 lockstep lower-triangular solve of 64x16 block; writes WsT (LDS) + Wg.
__device__ __forceinline__ void solve_lower(const float* P, const float* invd,
                                            const float* __restrict__ Wsrc16,
                                            float* WsT, float* __restrict__ Wg, int j) {
  const int tid = threadIdx.x;
  if (tid < 64) {
    const int n = tid & 15, rq = tid >> 4;
    float w16[16];
    #pragma unroll
    for (int i = 0; i < 16; ++i) w16[i] = Wsrc16[(size_t)(rq + 4 * i) * 16 + n];
    #pragma unroll
    for (int g = 0; g < 16; ++g) {
      floatx4 p[16];
      #pragma unroll
      for (int i = 0; i < 16; ++i) p[i] = *(const floatx4*)&P[(rq + 4 * i) * 68 + 4 * g];
      #pragma unroll
      for (int cj = 0; cj < 4; ++cj) {
        const int c = 4 * g + cj;
        float xc = __shfl(w16[c >> 2], ((c & 3) << 4) + n) * invd[c];
        if (rq == (c & 3)) w16[c >> 2] = xc;
        #pragma unroll
        for (int i = 0; i < 16; ++i) {
          int r = rq + 4 * i;
          if (r > c) w16[i] -= p[i][cj] * xc;
        }
      }
    }
    #pragma unroll
    for (int i = 0; i < 16; ++i) {
      WsT[n * 68 + rq + 4 * i] = w16[i];
      Wg[(size_t)(j + rq + 4 * i) * 16 + n] = w16[i];
    }
  }
}

// wave-0 lockstep upper-triangular solve (uses P upper = L^T mirror); writes Wg.
__device__ __forceinline__ void solve_upper(const float* P, const float* invd,
                                            const float* __restrict__ Wsrc16,
                                            float* __restrict__ Wg, int j) {
  const int tid = threadIdx.x;
  if (tid < 64) {
    const int n = tid & 15, rq = tid >> 4;
    float w16[16];
    #pragma unroll
    for (int i = 0; i < 16; ++i) w16[i] = Wsrc16[(size_t)(rq + 4 * i) * 16 + n];
    #pragma unroll
    for (int g = 15; g >= 0; --g) {
      floatx4 p[16];
      #pragma unroll
      for (int i = 0; i < 16; ++i) p[i] = *(const floatx4*)&P[(rq + 4 * i) * 68 + 4 * g];
      #pragma unroll
      for (int cj = 3; cj >= 0; --cj) {
        const int c = 4 * g + cj;
        float xc = __shfl(w16[c >> 2], ((c & 3) << 4) + n) * invd[c];
        if (rq == (c & 3)) w16[c >> 2] = xc;
        #pragma unroll
        for (int i = 0; i < 16; ++i) {
          int r = rq + 4 * i;
          if (r < c) w16[i] -= p[i][cj] * xc;
        }
      }
    }
    #pragma unroll
    for (int i = 0; i < 16; ++i)
      Wg[(size_t)(j + rq + 4 * i) * 16 + n] = w16[i];
  }
}

// setup_v3: 8 global barriers total.
// P0: Kss lower-tri tiles (own norms) + W init + potrf(0).  [1 bar]
// S(jb=0..6): tiles redundantly trsm their rows (owner tj==0 persists Lrow/LT),
//   syrk; WG0 potrf(jb+1); WG35 fwd-solve(jb-1) + W-update.  [7 bars]
// Tail (WG0, no barriers): fwd 6,7 + full backward + alpha_t.
__global__ __launch_bounds__(256) void setup_v3(const float* __restrict__ Zs,
                                                const int* __restrict__ Ys,
                                                const float* __restrict__ log_ls,
                                                const float* __restrict__ log_noise,
                                                float* __restrict__ K,
                                                float* __restrict__ sn,
                                                float* __restrict__ Wg,
                                                float* __restrict__ LT,
                                                float* __restrict__ Lrow,
                                                unsigned short* __restrict__ alpha_t,
                                                int* cnt, int* gen) {
  __shared__ float pf[13056];
  __shared__ float invd[64];
  const int wg = blockIdx.x, tid = threadIdx.x;

  int by = 0, accv = 0;
  while (accv + by + 1 <= wg) { accv += by + 1; ++by; }
  const int bx = wg - accv;

  // ---- P0 ----
  {
    const int rb = by * 64, cb = bx * 64;
    float* snl = pf;
    float* At = pf + 128;
    float* Bt = pf + 1216;
    float* Tile = pf + 2304;
    if (tid < 128) {
      int row = (tid < 64) ? rb + tid : cb + (tid - 64);
      const float4* rp = (const float4*)(Zs + (size_t)row * DD);
      float s0 = 0.f, s1 = 0.f, s2 = 0.f, s3 = 0.f;
      for (int i = 0; i < 256; i += 4) {
        float4 a = rp[i], b2 = rp[i + 1], c2 = rp[i + 2], d2 = rp[i + 3];
        s0 += a.x * a.x + a.y * a.y + a.z * a.z + a.w * a.w;
        s1 += b2.x * b2.x + b2.y * b2.y + b2.z * b2.z + b2.w * b2.w;
        s2 += c2.x * c2.x + c2.y * c2.y + c2.z * c2.z + c2.w * c2.w;
        s3 += d2.x * d2.x + d2.y * d2.y + d2.z * d2.z + d2.w * d2.w;
      }
      snl[tid] = (s0 + s1) + (s2 + s3);
      if (by == bx && tid < 64) sn[rb + tid] = snl[tid];
    }
    {
      int flat = wg * 256 + tid;
      if (flat < NS * NW) Wg[flat] = (Ys[flat >> 4] == (flat & 15)) ? 1.f : 0.f;
    }
    const int tx = tid & 15, ty = tid >> 4;
    const int srow = tid & 63, skq = (tid >> 6) << 2;
    float acc[4][4] = {};
    for (int kk = 0; kk < DD; kk += 16) {
      __syncthreads();
      float4 a = *(const float4*)(Zs + (size_t)(rb + srow) * DD + kk + skq);
      float4 b = *(const float4*)(Zs + (size_t)(cb + srow) * DD + kk + skq);
      At[(skq + 0) * 68 + srow] = a.x; At[(skq + 1) * 68 + srow] = a.y;
      At[(skq + 2) * 68 + srow] = a.z; At[(skq + 3) * 68 + srow] = a.w;
      Bt[(skq + 0) * 68 + srow] = b.x; Bt[(skq + 1) * 68 + srow] = b.y;
      Bt[(skq + 2) * 68 + srow] = b.z; Bt[(skq + 3) * 68 + srow] = b.w;
      __syncthreads();
      #pragma unroll
      for (int k = 0; k < 16; ++k) {
        floatx4 av = *(const floatx4*)&At[k * 68 + ty * 4];
        floatx4 bv = *(const floatx4*)&Bt[k * 68 + tx * 4];
        #pragma unroll
        for (int i = 0; i < 4; ++i)
          #pragma unroll
          for (int jj = 0; jj < 4; ++jj)
            acc[i][jj] = fmaf(av[i], bv[jj], acc[i][jj]);
      }
    }
    float inv2 = 0.5f * expf(-2.f * log_ls[0]);
    float noise = expf(2.f * log_noise[0]);
    #pragma unroll
    for (int i = 0; i < 4; ++i)
      #pragma unroll
      for (int jj = 0; jj < 4; ++jj) {
        int rl = ty * 4 + i, cl = tx * 4 + jj;
        int r = rb + rl, c = cb + cl;
        float d2 = fmaxf(snl[rl] + snl[64 + cl] - 2.f * acc[i][jj], 0.f);
        float v = expf(-d2 * inv2);
        if (r == c) v += noise;
        K[(size_t)r * NS + c] = v;
        if (wg == 0) Tile[rl * 68 + cl] = v;
      }
    if (wg == 0) {
      __syncthreads();
      potrf_tile(Tile, K, 0);
    }
  }
  gbar(cnt, gen);

  // ---- S(jb) ----
  for (int jb = 0; jb < 7; ++jb) {
    const int j = jb << 6;
    const int T = 7 - jb;
    const int nt = T * (T + 1) / 2;
    if (wg < nt) {
      int ti = 0, a2 = 0;
      while (a2 + ti + 1 <= wg) { a2 += ti + 1; ++ti; }
      const int tj = wg - a2;
      const int rbt = j + 64 + ti * 64, cbt = j + 64 + tj * 64;
      float* Ld = pf;
      float* A  = pf + 4352;
      float* B  = (ti == tj) ? A : pf + 8704;
      #pragma unroll
      for (int it = 0; it < 4; ++it) {
        int flat = tid + 256 * it;
        int r = flat >> 4, c4 = (flat & 15) * 4;
        *(floatx4*)&Ld[r * 68 + c4] = *(const floatx4*)&K[(size_t)(j + r) * NS + j + c4];
      }
      __syncthreads();
      if (tid < 64) invd[tid] = 1.f / Ld[tid * 68 + tid];
      __syncthreads();
      if (tid < 64) {
        float xr[64];
        const int row = rbt + tid;
        trsm_row(&K[(size_t)row * NS + j], Ld, invd, xr);
        #pragma unroll
        for (int c4 = 0; c4 < 16; ++c4)
          *(floatx4*)&A[tid * 68 + c4 * 4] = *(const floatx4*)&xr[c4 * 4];
        if (tj == 0) {
          float* lr = Lrow + ((size_t)jb * NS + row) * 64;
          #pragma unroll
          for (int c4 = 0; c4 < 16; ++c4)
            *(floatx4*)(lr + c4 * 4) = *(const floatx4*)&xr[c4 * 4];
          #pragma unroll
          for (int c = 0; c < 64; ++c)
            LT[(size_t)(j + c) * NS + row] = xr[c];
        }
      } else if (tid < 128 && ti != tj) {
        float xr[64];
        const int row = cbt + (tid - 64);
        trsm_row(&K[(size_t)row * NS + j], Ld, invd, xr);
        #pragma unroll
        for (int c4 = 0; c4 < 16; ++c4)
          *(floatx4*)&B[(tid - 64) * 68 + c4 * 4] = *(const floatx4*)&xr[c4 * 4];
      }
      __syncthreads();
      {
        const int tx = tid & 15, ty = tid >> 4;
        float acc[4][4] = {};
        for (int k = 0; k < 64; ++k) {
          float aa[4], bb[4];
          #pragma unroll
          for (int i = 0; i < 4; ++i) aa[i] = A[(ty * 4 + i) * 68 + k];
          #pragma unroll
          for (int i = 0; i < 4; ++i) bb[i] = B[(tx * 4 + i) * 68 + k];
          #pragma unroll
          for (int i = 0; i < 4; ++i)
            #pragma unroll
            for (int jj = 0; jj < 4; ++jj)
              acc[i][jj] = fmaf(aa[i], bb[jj], acc[i][jj]);
        }
        __syncthreads();
        #pragma unroll
        for (int i = 0; i < 4; ++i)
          #pragma unroll
          for (int jj = 0; jj < 4; ++jj) {
            float* cp = &K[(size_t)(rbt + ty * 4 + i) * NS + cbt + tx * 4 + jj];
            float nv = *cp - acc[i][jj];
            *cp = nv;
            if (wg == 0) Ld[(ty * 4 + i) * 68 + tx * 4 + jj] = nv;
          }
      }
      if (wg == 0) {
        __syncthreads();
        potrf_tile(Ld, K, j + 64);
      }
    } else if (wg == 35 && jb >= 1) {
      const int b = jb - 1, j2 = b << 6;
      float* P = pf;
      float* WsT = pf + 4352;
      #pragma unroll
      for (int it = 0; it < 4; ++it) {
        int flat = tid + 256 * it;
        int r = flat >> 4, c4 = (flat & 15) * 4;
        *(floatx4*)&P[r * 68 + c4] = *(const floatx4*)&K[(size_t)(j2 + r) * NS + j2 + c4];
      }
      __syncthreads();
      if (tid < 64) invd[tid] = 1.f / P[tid * 68 + tid];
      solve_lower(P, invd, Wg + (size_t)j2 * 16, WsT, Wg, j2);
      __syncthreads();
      const int nrows = NS - j2 - 64;
      for (int flat = tid; flat < nrows * 16; flat += 256) {
        int row = j2 + 64 + (flat >> 4), nn = flat & 15;
        float s = Wg[(size_t)row * 16 + nn];
        const float* lr = Lrow + ((size_t)b * NS + row) * 64;
        #pragma unroll
        for (int g = 0; g < 16; ++g) {
          floatx4 lv = *(const floatx4*)(lr + 4 * g);
          floatx4 wv = *(const floatx4*)&WsT[nn * 68 + 4 * g];
          s -= lv.x * wv.x + lv.y * wv.y + lv.z * wv.z + lv.w * wv.w;
        }
        Wg[(size_t)row * 16 + nn] = s;
      }
    }
    gbar(cnt, gen);
  }

  // ---- tail (WG0 only) ----
  if (wg != 0) return;
  {
    float* P = pf;
    float* WsT = pf + 4352;
    for (int b = 6; b <= 7; ++b) {
      const int j2 = b << 6;
      __syncthreads();
      #pragma unroll
      for (int it = 0; it < 4; ++it) {
        int flat = tid + 256 * it;
        int r = flat >> 4, c4 = (flat & 15) * 4;
        *(floatx4*)&P[r * 68 + c4] = *(const floatx4*)&K[(size_t)(j2 + r) * NS + j2 + c4];
      }
      __syncthreads();
      if (tid < 64) invd[tid] = 1.f / P[tid * 68 + tid];
      solve_lower(P, invd, Wg + (size_t)j2 * 16, WsT, Wg, j2);
      __syncthreads();
      if (b == 6) {
        for (int flat = tid; flat < 64 * 16; flat += 256) {
          int row = 448 + (flat >> 4), nn = flat & 15;
          float s = Wg[(size_t)row * 16 + nn];
          const float* lr = Lrow + ((size_t)6 * NS + row) * 64;
          #pragma unroll
          for (int g = 0; g < 16; ++g) {
            floatx4 lv = *(const floatx4*)(lr + 4 * g);
            floatx4 wv = *(const floatx4*)&WsT[nn * 68 + 4 * g];
            s -= lv.x * wv.x + lv.y * wv.y + lv.z * wv.z + lv.w * wv.w;
          }
          Wg[(size_t)row * 16 + nn] = s;
        }
        __syncthreads();
      }
    }
    for (int jb2 = 7; jb2 >= 0; --jb2) {
      const int j2 = jb2 << 6;
      __syncthreads();
      #pragma unroll
      for (int it = 0; it < 4; ++it) {
        int flat = tid + 256 * it;
        int r = flat >> 4, c4 = (flat & 15) * 4;
        *(floatx4*)&P[r * 68 + c4] = *(const floatx4*)&K[(size_t)(j2 + r) * NS + j2 + c4];
      }
      __syncthreads();
      if (tid < 64) invd[tid] = 1.f / P[tid * 68 + tid];
      solve_upper(P, invd, Wg + (size_t)j2 * 16, Wg, j2);
      __syncthreads();
      if (jb2 > 0) {
        for (int e = tid; e < 1024; e += 256) {
          int c = e >> 4, n = e & 15;
          WsT[n * 68 + c] = Wg[(size_t)(j2 + c) * 16 + n];
        }
        __syncthreads();
        for (int flat = tid; flat < j2 * 16; flat += 256) {
          int r = flat >> 4, nn = flat & 15;
          float s = Wg[(size_t)r * 16 + nn];
          const float* lr = LT + (size_t)r * NS + j2;
          #pragma unroll
          for (int g = 0; g < 16; ++g) {
            floatx4 lv = *(const floatx4*)(lr + 4 * g);
            floatx4 wv = *(const floatx4*)&WsT[nn * 68 + 4 * g];
            s -= lv.x * wv.x + lv.y * wv.y + lv.z * wv.z + lv.w * wv.w;
          }
          Wg[(size_t)r * 16 + nn] = s;
        }
        __syncthreads();
      }
    }
    for (int i = tid; i < NS * NW; i += 256)
      alpha_t[(size_t)(i & 15) * NS + (i >> 4)] = bf_rne(Wg[i]);
  }
}

// fused: split-bf16 MFMA Gram -> exp -> MFMA PV -> softmax
__global__ __launch_bounds__(512) void fused_v2(const float* __restrict__ Zq,
                                                const float* __restrict__ Zs,
                                                const float* __restrict__ sn,
                                                const unsigned short* __restrict__ alpha_t,
                                                const float* __restrict__ log_ls,
                                                float* __restrict__ out) {
  __shared__ __align__(16) unsigned short LB[32768];
  __shared__ float qnl[128];
  __shared__ float snl[256];
  unsigned short* AhB = LB;
  unsigned short* AlB = LB + 4096;
  unsigned short* BhB = LB + 8192;
  unsigned short* BlB = LB + 16384;
  unsigned short* KqB = LB;

  const int tid = threadIdx.x;
  const int lane = tid & 63;
  const int w = tid >> 6;
  const int wm = w >> 2, wn = w & 3;
  const int l15 = lane & 15, l4 = lane >> 4;
  const int rb = blockIdx.x * 128;
  const float inv2 = 0.5f * __expf(-2.f * log_ls[0]);
  const unsigned swz = (unsigned)((l15 & 7) << 3);

  if (tid < 128) qnl[tid] = 0.f;
  __syncthreads();

  const int qrow0 = tid >> 3;
  const int qk0 = (tid & 7) * 4;
  const int qrow1 = 64 + qrow0;

  floatx4 facc = {0.f, 0.f, 0.f, 0.f};

  for (int cc = 0; cc < NS; cc += 256) {
    if (tid < 256) snl[tid] = sn[cc + tid];
    floatx4 acc[4][4];
    #pragma unroll
    for (int a = 0; a < 4; ++a)
      #pragma unroll
      for (int b = 0; b < 4; ++b) acc[a][b] = (floatx4){0.f, 0.f, 0.f, 0.f};

    float4 pq0 = *(const float4*)(Zq + (size_t)(rb + qrow0) * DD + qk0);
    float4 pq1 = *(const float4*)(Zq + (size_t)(rb + qrow1) * DD + qk0);
    float4 ps[4];
    #pragma unroll
    for (int u = 0; u < 4; ++u) {
      int idx = tid + (u << 9);
      ps[u] = *(const float4*)(Zs + (size_t)(cc + (idx >> 3)) * DD + ((idx & 7) * 4));
    }

    for (int kt = 0; kt < 32; ++kt) {
      STASH(AhB, AlB, qrow0, qk0, pq0);
      STASH(AhB, AlB, qrow1, qk0, pq1);
      #pragma unroll
      for (int u = 0; u < 4; ++u) {
        int idx = tid + (u << 9);
        int srow = idx >> 3, sk0 = (idx & 7) * 4;
        STASH(BhB, BlB, srow, sk0, ps[u]);
      }
      if (cc == 0) {
        float s0 = pq0.x * pq0.x + pq0.y * pq0.y + pq0.z * pq0.z + pq0.w * pq0.w;
        float s1 = pq1.x * pq1.x + pq1.y * pq1.y + pq1.z * pq1.z + pq1.w * pq1.w;
        #pragma unroll
        for (int d = 1; d < 8; d <<= 1) { s0 += __shfl_xor(s0, d); s1 += __shfl_xor(s1, d); }
        if ((tid & 7) == 0) { qnl[qrow0] += s0; qnl[qrow1] += s1; }
      }
      __syncthreads();
      if (kt < 31) {
        int kk2 = (kt + 1) << 5;
        pq0 = *(const float4*)(Zq + (size_t)(rb + qrow0) * DD + kk2 + qk0);
        pq1 = *(const float4*)(Zq + (size_t)(rb + qrow1) * DD + kk2 + qk0);
        #pragma unroll
        for (int u = 0; u < 4; ++u) {
          int idx = tid + (u << 9);
          ps[u] = *(const float4*)(Zs + (size_t)(cc + (idx >> 3)) * DD + kk2 + ((idx & 7) * 4));
        }
      }
      short8x ah[4], al[4], bh[4], bl[4];
      #pragma unroll
      for (int mi = 0; mi < 4; ++mi) {
        unsigned e = (unsigned)((wm * 64 + mi * 16 + l15) * 32 + 8 * l4) ^ swz;
        ah[mi] = *(const short8x*)&AhB[e];
        al[mi] = *(const short8x*)&AlB[e];
      }
      #pragma unroll
      for (int ni = 0; ni < 4; ++ni) {
        unsigned e = (unsigned)((wn * 64 + ni * 16 + l15) * 32 + 8 * l4) ^ swz;
        bh[ni] = *(const short8x*)&BhB[e];
        bl[ni] = *(const short8x*)&BlB[e];
      }
      #pragma unroll
      for (int mi = 0; mi < 4; ++mi)
        #pragma unroll
        for (int ni = 0; ni < 4; ++ni) {
          acc[mi][ni] = __builtin_amdgcn_mfma_f32_16x16x32_bf16(ah[mi], bh[ni], acc[mi][ni], 0, 0, 0);
          acc[mi][ni] = __builtin_amdgcn_mfma_f32_16x16x32_bf16(ah[mi], bl[ni], acc[mi][ni], 0, 0, 0);
          acc[mi][ni] = __builtin_amdgcn_mfma_f32_16x16x32_bf16(al[mi], bh[ni], acc[mi][ni], 0, 0, 0);
        }
      __syncthreads();
    }

    short8x bfr[8];
    #pragma unroll
    for (int s = 0; s < 8; ++s)
      bfr[s] = *(const short8x*)(alpha_t + ((size_t)l15 * NS + cc + 32 * s + 8 * l4));

    #pragma unroll
    for (int mi = 0; mi < 4; ++mi)
      #pragma unroll
      for (int rr = 0; rr < 4; ++rr) {
        int row_l = wm * 64 + mi * 16 + l4 * 4 + rr;
        float qv = qnl[row_l];
        unsigned sw = (unsigned)((row_l & 7) << 3);
        #pragma unroll
        for (int ni = 0; ni < 4; ++ni) {
          int col = wn * 64 + ni * 16 + l15;
          float d2 = fmaxf(qv + snl[col] - 2.f * acc[mi][ni][rr], 0.f);
          float kq = __expf(-d2 * inv2);
          KqB[(unsigned)(row_l * 256 + col) ^ sw] = bf_rne(kq);
        }
      }
    __syncthreads();
    #pragma unroll
    for (int s = 0; s < 8; ++s) {
      unsigned e = (unsigned)((w * 16 + l15) * 256 + 32 * s + 8 * l4) ^ swz;
      short8x ak = *(const short8x*)&KqB[e];
      facc = __builtin_amdgcn_mfma_f32_16x16x32_bf16(ak, bfr[s], facc, 0, 0, 0);
    }
    __syncthreads();
  }

  #pragma unroll
  for (int r = 0; r < 4; ++r) {
    float v = facc[r];
    float m = v;
    #pragma unroll
    for (int d = 1; d < 16; d <<= 1) m = fmaxf(m, __shfl_xor(m, d));
    float e = __expf(v - m);
    float s = e;
    #pragma unroll
    for (int d = 1; d < 16; d <<= 1) s += __shfl_xor(s, d);
    out[(size_t)(rb + w * 16 + l4 * 4 + r) * NW + l15] = e / s;
  }
}

extern "C" void kernel_launch(void* const* d_in, const int* in_sizes, int n_in,
                              void* d_out, int out_size, void* d_ws, size_t ws_size,
                              hipStream_t stream) {
  (void)in_sizes; (void)n_in; (void)out_size; (void)ws_size;
  const float* Zs = (const float*)d_in[0];
  const int*   Ys = (const int*)d_in[1];
  const float* Zq = (const float*)d_in[2];
  const float* log_ls = (const float*)d_in[3];
  const float* log_noise = (const float*)d_in[4];
  float* out = (float*)d_out;

  float* ws = (float*)d_ws;
  float* K  = ws;                                    // 262144 f32
  float* sn = K + (size_t)NS * NS;                   // 512
  unsigned short* alpha_t = (unsigned short*)(sn + NS);  // 4096 f32 slots
  float* Wg   = sn + NS + 4096;                      // [512][16]
  float* LT   = Wg + (size_t)NS * NW;                // [512][512]: LT[c][r] = L[r][c]
  float* Lrow = LT + (size_t)NS * NS;                // [8][512][64]
  int* flags = (int*)(Lrow + (size_t)8 * NS * 64);   // {cnt, gen}

  hipMemsetAsync(flags, 0, 2 * sizeof(int), stream);
  setup_v3<<<NWG, 256, 0, stream>>>(Zs, Ys, log_ls, log_noise, K, sn, Wg, LT, Lrow,
                                    alpha_t, flags, flags + 1);
  fused_v2<<<NQ / 128, 512, 0, stream>>>(Zq, Zs, sn, alpha_t, log_ls, out);
}